// Round 6
// baseline (219.241 us; speedup 1.0000x reference)
//
#include <hip/hip_runtime.h>
#include <math.h>

// RPNLayer: logits = x(32768,1024) @ W(1024,16) + b; per-anchor (8) 2-class
// log-softmax CE over valid anchors; argmax + candidate mask.
//
// R6 structure: channel-sweep + 2x occupancy + split epilogue.
//   Evidence: R2/R4/R5 (three different x-delivery schemes) all plateau at
//   ~1.6-1.9 TB/s x-read while harness fills hit 7 TB/s. Common cause:
//   64-row tiles -> 64-256B bursts at exactly 4KB stride, all waves
//   phase-locked on the same K-offsets -> HBM/L2 channel camping
//   (R2's 830 GB/s ~ peak/8). Plus grid 512 = only 2 blocks/CU.
//   - rpn_main: grid 1024 = (512 row-blocks) x (2 K-halves) -> 4 blocks/CU,
//     up to 32 waves/CU (main has no transcendentals; ~44 VGPR).
//     Wave kse = (wave + blockIdx)&7 and chunk order chr = (blockIdx>>3)&3
//     rotate per block -> at any instant blocks read different byte-offsets
//     within rows -> requests sweep all channels. W stays wave-uniform
//     (scalar s_load pipe). No barriers in the main loop (R4 inner loop).
//     Block reduces its 8 wave-partials in LDS and writes a 64x16 f32
//     partial tile to ws; no labels/CE in main.
//   - rpn_final: 128 blocks x 256 thr, 1 thread/row: sum 2 K-half partials
//     + bias, CE/argmax/mask, block-reduce loss, atomicAdd; last block
//     (ticket) writes out[0] = S / max(C,1).
//
// d_out (float32): [0] loss | [1..262144] predict | [262145..524288] mask
// ws: [0]=loss sum [1]=count [2]=ticket [3]=pad | [8..] partials 2x2MB

#define ROWS   64
#define NW     8
#define KSL    64            // K floats per wave (1024 / (2 kb * 8 waves))
#define KCH    16            // K floats per chunk (one 64B line per lane)
#define NCH    4             // KSL/KCH
#define RSTR   132           // LDS reduction row stride (floats)
#define PART_STRIDE (32768u * 16u)   // floats per K-half partial (2 MB)

__global__ __launch_bounds__(512, 4)
void rpn_main(const float* __restrict__ x, const float* __restrict__ W,
              float* __restrict__ ws)
{
    __shared__ float red[ROWS * RSTR];       // 33792 B -> 4 blocks/CU fits

    const int tid  = threadIdx.x;
    const int lane = tid & 63;
    const int wv   = __builtin_amdgcn_readfirstlane(tid >> 6);
    const int rb   = blockIdx.x & 511;       // row-block
    const int kb   = blockIdx.x >> 9;        // K-half 0/1
    const int row0 = rb * ROWS;
    const int kse  = (wv + blockIdx.x) & 7;  // rotated wave->K-slice
    const int chr  = (blockIdx.x >> 3) & 3;  // rotated chunk start

    const float* xp = x + (size_t)(row0 + lane) * 1024 + kb * 512 + kse * KSL;
    const float* wk = W + (size_t)(kb * 512 + kse * KSL) * 16;

    float acc[16];
#pragma unroll
    for (int c = 0; c < 16; ++c) acc[c] = 0.f;

    // prefetch first (rotated) chunk: 16 k = 4 float4 (one 64B line)
    float4 pf[4];
#pragma unroll
    for (int j = 0; j < 4; ++j)
        pf[j] = *(const float4*)(xp + chr * KCH + j * 4);

#define FMA16(V, WROW)                                            \
    do {                                                          \
        const float* _w = (WROW);                                 \
        _Pragma("unroll")                                         \
        for (int c = 0; c < 16; ++c)                              \
            acc[c] = fmaf((V), _w[c], acc[c]);                    \
    } while (0)

#pragma unroll
    for (int ci = 0; ci < NCH; ++ci) {
        const int ch  = (ci + chr) & 3;
        const int chn = (ci + 1 + chr) & 3;
        const float* wc = wk + ch * (KCH * 16);   // wave-uniform -> s_load
#pragma unroll
        for (int j = 0; j < 4; ++j) {
            float4 v = pf[j];
            if (ci != NCH - 1)
                pf[j] = *(const float4*)(xp + chn * KCH + j * 4);
            FMA16(v.x, wc + (j * 4 + 0) * 16);
            FMA16(v.y, wc + (j * 4 + 1) * 16);
            FMA16(v.z, wc + (j * 4 + 2) * 16);
            FMA16(v.w, wc + (j * 4 + 3) * 16);
        }
    }
#undef FMA16

    // ---- 8-way wave reduction in LDS, then partial tile -> ws ----
    __syncthreads();                         // cheap; orders red lifetimes
    {
        float* rp = red + lane * RSTR + wv * 16;
        *(float4*)(rp + 0)  = make_float4(acc[0],  acc[1],  acc[2],  acc[3]);
        *(float4*)(rp + 4)  = make_float4(acc[4],  acc[5],  acc[6],  acc[7]);
        *(float4*)(rp + 8)  = make_float4(acc[8],  acc[9],  acc[10], acc[11]);
        *(float4*)(rp + 12) = make_float4(acc[12], acc[13], acc[14], acc[15]);
    }
    __syncthreads();

    if (tid < 256) {
        const int row = tid >> 2;
        const int c0  = (tid & 3) * 4;
        float4 s = make_float4(0.f, 0.f, 0.f, 0.f);
#pragma unroll
        for (int k = 0; k < NW; ++k) {
            float4 t = *(const float4*)(red + row * RSTR + k * 16 + c0);
            s.x += t.x; s.y += t.y; s.z += t.z; s.w += t.w;
        }
        float* dst = ws + 8 + (size_t)kb * PART_STRIDE
                   + (size_t)(row0 + row) * 16 + c0;
        *(float4*)dst = s;                   // coalesced 4KB/block
    }
}

__global__ __launch_bounds__(256, 4)
void rpn_final(const float* __restrict__ b, const int* __restrict__ lab,
               float* __restrict__ out, float* __restrict__ ws)
{
    __shared__ float rsum[8];
    const int tid = threadIdx.x;
    const int row = blockIdx.x * 256 + tid;

    const float* p0 = ws + 8 + (size_t)row * 16;
    const float* p1 = p0 + PART_STRIDE;

    float L[16];
#pragma unroll
    for (int q = 0; q < 4; ++q) {
        float4 a0 = *(const float4*)(p0 + q * 4);
        float4 a1 = *(const float4*)(p1 + q * 4);
        L[q * 4 + 0] = a0.x + a1.x + b[q * 4 + 0];
        L[q * 4 + 1] = a0.y + a1.y + b[q * 4 + 1];
        L[q * 4 + 2] = a0.z + a1.z + b[q * 4 + 2];
        L[q * 4 + 3] = a0.w + a1.w + b[q * 4 + 3];
    }

    const int* labp = lab + (size_t)row * 8;
    float pv[8], mv[8];
    float lsum = 0.f, lcnt = 0.f;
#pragma unroll
    for (int a = 0; a < 8; ++a) {
        float l0 = L[2 * a], l1 = L[2 * a + 1];
        int   lb = labp[a];
        int   pred  = (l1 > l0) ? 1 : 0;          // strict: tie -> class 0
        int   valid = (lb != -1);
        float m   = fmaxf(l0, l1);
        float lse = m + logf(expf(l0 - m) + expf(l1 - m));
        float nll = lse - ((lb == 1) ? l1 : l0);
        if (valid) { lsum += nll; lcnt += 1.f; }
        pv[a] = (float)pred;
        mv[a] = (pred && valid) ? 1.f : 0.f;
    }

    float* predp = out + 1 + (size_t)row * 8;
    float* maskp = out + 1 + 262144 + (size_t)row * 8;
    *(float4*)(predp)     = make_float4(pv[0], pv[1], pv[2], pv[3]);
    *(float4*)(predp + 4) = make_float4(pv[4], pv[5], pv[6], pv[7]);
    *(float4*)(maskp)     = make_float4(mv[0], mv[1], mv[2], mv[3]);
    *(float4*)(maskp + 4) = make_float4(mv[4], mv[5], mv[6], mv[7]);

    // block loss reduction: wave shuffle, then 4-wave LDS combine
#pragma unroll
    for (int off = 32; off > 0; off >>= 1) {
        lsum += __shfl_down(lsum, off, 64);
        lcnt += __shfl_down(lcnt, off, 64);
    }
    if ((tid & 63) == 0) {
        rsum[(tid >> 6) * 2]     = lsum;
        rsum[(tid >> 6) * 2 + 1] = lcnt;
    }
    __syncthreads();
    if (tid == 0) {
        float S = rsum[0] + rsum[2] + rsum[4] + rsum[6];
        float C = rsum[1] + rsum[3] + rsum[5] + rsum[7];
        atomicAdd(&ws[0], S);
        atomicAdd(&ws[1], C);
        __threadfence();
        unsigned int old = atomicAdd((unsigned int*)(ws + 2), 1u);
        if (old == gridDim.x - 1) {          // last block finishes the loss
            float Sf = atomicAdd(&ws[0], 0.f);
            float Cf = atomicAdd(&ws[1], 0.f);
            out[0] = Sf / fmaxf(Cf, 1.f);
        }
    }
}

extern "C" void kernel_launch(void* const* d_in, const int* in_sizes, int n_in,
                              void* d_out, int out_size, void* d_ws, size_t ws_size,
                              hipStream_t stream)
{
    const float* x   = (const float*)d_in[0];   // (64,512,1024) f32
    const float* W   = (const float*)d_in[1];   // (1024,16) f32
    const float* b   = (const float*)d_in[2];   // (16,) f32
    const int*   lab = (const int*)d_in[3];     // (64,512,8) i32 in {-1,0,1}
    float* out = (float*)d_out;
    float* ws  = (float*)d_ws;

    hipMemsetAsync(ws, 0, 16, stream);
    rpn_main<<<dim3(1024), dim3(512), 0, stream>>>(x, W, ws);
    rpn_final<<<dim3(128), dim3(256), 0, stream>>>(b, lab, out, ws);
}